// Round 10
// baseline (136.995 us; speedup 1.0000x reference)
//
#include <hip/hip_runtime.h>
#include <stdint.h>

// Problem constants (from reference setup_inputs)
#define BATCH 4096
#define ISZ   512
#define OSZ   512
#define KDIM  4096           // contraction dim: k = i*8 + d

// GEMM tiling
#define TM 128
#define TN 128
#define BK 128
#define SPLITK 8

typedef __bf16 bf16x8 __attribute__((ext_vector_type(8)));
typedef float  f32x4  __attribute__((ext_vector_type(4)));

__device__ __forceinline__ unsigned short f2bf(float f) {
    uint32_t u = __float_as_uint(f);
    u = (u + 0x7FFFu + ((u >> 16) & 1u)) >> 16;
    return (unsigned short)u;
}

// Fused prep (R9-proven): (a) jac = jacobi8(tanh(x)) [blocks 0..NJAC),
// (b) coef fp32->bf16 [blocks NJAC..NJAC+NCVT).
#define NJAC ((BATCH * ISZ) / 256)          // 8192 blocks
#define NCVT ((OSZ * KDIM) / 4 / 256)       // 2048 blocks
__global__ __launch_bounds__(256) void prep(
    const float* __restrict__ x, unsigned short* __restrict__ jac,
    const float* __restrict__ coef, unsigned short* __restrict__ coefb)
{
    int bid = blockIdx.x;
    if (bid < NJAC) {
        int idx = bid * 256 + threadIdx.x;
        float t  = tanhf(x[idx]);
        float p1 = 2.0f * t;
        float p2 = (1.875f     * t) * p1 - 0.75f;
        float p3 = (1.8666667f * t) * p2 - 0.8f        * p1;
        float p4 = (1.875f     * t) * p3 - 0.83333333f * p2;
        float p5 = (1.8857143f * t) * p4 - 0.85714287f * p3;
        float p6 = (1.8958333f * t) * p5 - 0.875f      * p4;
        float p7 = (1.9047619f * t) * p6 - 0.88888889f * p5;
        uint4 o;
        o.x = 0x3F80u | ((uint32_t)f2bf(p1) << 16);     // bf16(1.0) | p1
        o.y = (uint32_t)f2bf(p2) | ((uint32_t)f2bf(p3) << 16);
        o.z = (uint32_t)f2bf(p4) | ((uint32_t)f2bf(p5) << 16);
        o.w = (uint32_t)f2bf(p6) | ((uint32_t)f2bf(p7) << 16);
        *reinterpret_cast<uint4*>(jac + (size_t)idx * 8) = o;
    } else {
        int idx = (bid - NJAC) * 256 + threadIdx.x;
        float4 v = reinterpret_cast<const float4*>(coef)[idx];
        uint2 o;
        o.x = (uint32_t)f2bf(v.x) | ((uint32_t)f2bf(v.y) << 16);
        o.y = (uint32_t)f2bf(v.z) | ((uint32_t)f2bf(v.w) << 16);
        reinterpret_cast<uint2*>(coefb)[idx] = o;
    }
}

// R10 GEMM: A-only LDS, B direct-from-global.
// R9 audit: per block-iter 2250 cy = MFMA 621 + LDS r/w 1030 + barrier ~600;
// LDS pipe + barrier tax co-bind the k-loop at ~30us across ALL prior
// variants. Fix: (1) B fragments are per-lane global_load_dwordx4 straight
// from L2-hot coefb (16 rows x 64B fully-coalesced; no LDS round-trip, no
// register double-buffer -> avoids R7's VGPR cliff; loads are short-lived
// 16-VGPR sets per ks-step). (2) LDS holds A only (32 KB) -> BK=128 cuts
// barrier count to 4/block. (3) splitK=8 -> 1024 blocks; launch_bounds
// (256,4) caps VGPR at 128 -> 4 blocks/CU to cross-cover drains.
// A staged via global_load_lds width=16 (wave-uniform base + lane*16 dest).
// LDS slots (16B chunks, 16/row) XOR-swizzled: (row,c) at row*16 +
// (c ^ (row&15)) -> fragment reads 2-way/bank-group (free per m136);
// swizzle on per-lane *source* col, permutation within a 256B row region
// so DMA coalescing holds.
// 128x128 block tile, 256 threads = 4 waves (2x2), wave tile 64x64 via
// 4x4 of mfma_f32_16x16x32_bf16 (A/B/C layouts verified R1-R9).
__global__ __launch_bounds__(256, 4) void gemm_bg(
    const unsigned short* __restrict__ A,   // [M][K] bf16 bits (jac)
    const unsigned short* __restrict__ Bm,  // [N][K] bf16 bits (coefb)
    unsigned short* __restrict__ Cp,        // [SPLITK][M][N] bf16 partials
    int M, int N, int K)
{
    __shared__ __align__(16) unsigned short As[TM * BK];   // 32 KB

    const int tid  = threadIdx.x;
    const int wave = tid >> 6;
    const int lane = tid & 63;
    const int wm   = (wave >> 1) * 64;      // wave row offset in tile
    const int wn   = (wave & 1) * 64;       // wave col offset in tile

    const size_t baseA = (size_t)blockIdx.x * TM * K;
    const int    n0    = blockIdx.y * TN;
    const int kper = K / SPLITK;            // 512
    const int kbeg = blockIdx.z * kper;
    const int kend = kbeg + kper;           // 4 iters of BK=128

    f32x4 acc[4][4] = {};

    const int mrow = lane & 15;             // m/n within 16x16 tile
    const int kc   = lane >> 4;             // 16B-chunk column offset within k

    // B fragment row base pointers (per-lane, fixed across iters)
    const unsigned short* browp[4];
    #pragma unroll
    for (int ni = 0; ni < 4; ++ni)
        browp[ni] = Bm + (size_t)(n0 + wn + ni * 16 + mrow) * K + kc * 8;

    for (int k0 = kbeg; k0 < kend; k0 += BK) {
        // ---- A staging: 128x128 bf16 = 32 KB = 2048 chunks of 16B;
        // 256 threads x 8 its. slot s: row = s>>4, src col = (s&15)^(row&15);
        // dest = wave-uniform base + lane*16 = s*16.
        #pragma unroll
        for (int it = 0; it < 8; ++it) {
            int s    = it * 256 + tid;
            int row  = s >> 4;
            int csrc = (s & 15) ^ (row & 15);
            const unsigned short* gA = A + baseA + (size_t)row * K + k0 + csrc * 8;
            unsigned short* lA = As + (size_t)(it * 256 + wave * 64) * 8;
            __builtin_amdgcn_global_load_lds(
                (const __attribute__((address_space(1))) uint32_t*)gA,
                (__attribute__((address_space(3))) uint32_t*)lA, 16, 0, 0);
        }
        __syncthreads();   // drains vmcnt for the A DMA

        #pragma unroll
        for (int ks = 0; ks < BK; ks += 32) {
            bf16x8 aF[4], bF[4];
            const int cbase = (ks >> 3) + kc;      // 16B chunk col in [0,16)
            // B: just-in-time global loads (L1/L2-hot, coalesced 64B rows)
            #pragma unroll
            for (int ni = 0; ni < 4; ++ni)
                bF[ni] = *reinterpret_cast<const bf16x8*>(browp[ni] + k0 + ks);
            #pragma unroll
            for (int mi = 0; mi < 4; ++mi) {
                int r = wm + mi * 16 + mrow;
                int slot = r * 16 + (cbase ^ (r & 15));
                aF[mi] = *reinterpret_cast<const bf16x8*>(As + (size_t)slot * 8);
            }
            #pragma unroll
            for (int mi = 0; mi < 4; ++mi)
                #pragma unroll
                for (int ni = 0; ni < 4; ++ni)
                    acc[mi][ni] = __builtin_amdgcn_mfma_f32_16x16x32_bf16(
                        aF[mi], bF[ni], acc[mi][ni], 0, 0, 0);
        }
        __syncthreads();   // fences As reuse next iter
    }

    // bf16 partials, plain stores (R3: atomics = ~50us TCC serialization).
    // C/D layout (m89-verified): col = lane&15, row = (lane>>4)*4 + r
    unsigned short* Cz = Cp + (size_t)blockIdx.z * M * N;
    const int orow = blockIdx.x * TM + wm + (lane >> 4) * 4;
    const int ocol = blockIdx.y * TN + wn + (lane & 15);
    #pragma unroll
    for (int mi = 0; mi < 4; ++mi)
        #pragma unroll
        for (int ni = 0; ni < 4; ++ni)
            #pragma unroll
            for (int r = 0; r < 4; ++r)
                Cz[(size_t)(orow + mi * 16 + r) * N + ocol + ni * 16] =
                    f2bf(acc[mi][ni][r]);
}

// out = sum over SPLITK bf16 partials (fp32 accumulate), 4 outputs/thread
__global__ __launch_bounds__(256) void reduce_k(
    const unsigned short* __restrict__ part, float* __restrict__ out, int n4)
{
    int idx = blockIdx.x * 256 + threadIdx.x;
    if (idx >= n4) return;
    const uint2* p = reinterpret_cast<const uint2*>(part);   // 4 bf16 / uint2
    float s0 = 0.f, s1 = 0.f, s2 = 0.f, s3 = 0.f;
    #pragma unroll
    for (int z = 0; z < SPLITK; ++z) {
        uint2 v = p[(size_t)z * n4 + idx];
        s0 += __uint_as_float((v.x & 0xFFFFu) << 16);
        s1 += __uint_as_float(v.x & 0xFFFF0000u);
        s2 += __uint_as_float((v.y & 0xFFFFu) << 16);
        s3 += __uint_as_float(v.y & 0xFFFF0000u);
    }
    float4 o = {s0, s1, s2, s3};
    reinterpret_cast<float4*>(out)[idx] = o;
}

extern "C" void kernel_launch(void* const* d_in, const int* in_sizes, int n_in,
                              void* d_out, int out_size, void* d_ws, size_t ws_size,
                              hipStream_t stream)
{
    const float* x    = (const float*)d_in[0];   // [4096][512]
    const float* coef = (const float*)d_in[1];   // [512][512][8]
    float* out = (float*)d_out;                  // [4096][512]

    // workspace: bf16 partials [SPLITK][4096][512] (32 MB)
    //          + coef bf16 [512][4096] (4 MB) + jac bf16 [4096][4096] (32 MB)
    unsigned short* part  = (unsigned short*)d_ws;
    unsigned short* coefb = part + (size_t)SPLITK * BATCH * OSZ;
    unsigned short* jac   = coefb + (size_t)OSZ * KDIM;

    prep<<<NJAC + NCVT, 256, 0, stream>>>(x, jac, coef, coefb);

    dim3 grid(BATCH / TM, OSZ / TN, SPLITK);     // 32 x 4 x 8 = 1024 blocks
    gemm_bg<<<grid, 256, 0, stream>>>(jac, coefb, part, BATCH, OSZ, KDIM);

    int n4r = (BATCH * OSZ) / 4;                 // 524,288
    reduce_k<<<(n4r + 255) / 256, 256, 0, stream>>>(part, out, n4r);
}

// Round 11
// 100.159 us; speedup vs baseline: 1.3678x; 1.3678x over previous
//
#include <hip/hip_runtime.h>
#include <stdint.h>

// Problem constants (from reference setup_inputs)
#define BATCH 4096
#define ISZ   512
#define OSZ   512
#define KDIM  4096           // contraction dim: k = i*8 + d

// GEMM tiling
#define TM 128
#define TN 128
#define BK 64
#define SPLITK 4

typedef __bf16 bf16x8 __attribute__((ext_vector_type(8)));
typedef float  f32x16 __attribute__((ext_vector_type(16)));

__device__ __forceinline__ unsigned short f2bf(float f) {
    uint32_t u = __float_as_uint(f);
    u = (u + 0x7FFFu + ((u >> 16) & 1u)) >> 16;
    return (unsigned short)u;
}

// flat fp32 -> bf16 convert (coef already k-contiguous: [O][I][D] -> [O][K])
__global__ __launch_bounds__(256) void convert_bf16(
    const float* __restrict__ src, unsigned short* __restrict__ dst, int n4)
{
    int idx = blockIdx.x * 256 + threadIdx.x;
    if (idx >= n4) return;
    float4 v = reinterpret_cast<const float4*>(src)[idx];
    uint2 o;
    o.x = (uint32_t)f2bf(v.x) | ((uint32_t)f2bf(v.y) << 16);
    o.y = (uint32_t)f2bf(v.z) | ((uint32_t)f2bf(v.w) << 16);
    reinterpret_cast<uint2*>(dst)[idx] = o;
}

// Fused Jacobi + GEMM (R6 structure - best measured total, 98.8us), with the
// ONE change for R11: MFMA shape 16x16x32 -> 32x32x16 (m119: 2495 vs 2176 TF
// ceiling; halves MFMA instruction count per iter in an issue-co-bound loop).
// Standing invariant (R2-R10): the 2-barrier LDS k-loop is ~30-33us across
// fusion/buffering/occupancy/tile/B-path variants (= learn_hip m131-141
// plateau); per-lane global B-loads regress (R7, R10 - L1 thrash + exposed
// VMEM latency in the MFMA chain).
// Wave tile 64x64 = 2x2 of 32x32x16. LDS layout and staging identical to R6:
// 16B chunks, XOR swizzle slot = row*8 + (c ^ (row&7)) (conflicts == 0
// measured R2-R9); B via global_load_lds (wave-uniform base + lane*16 dest,
// swizzle on per-lane source addr); A = jacobi8(tanh(x)) computed in-block
// (1024 evals/iter, 4/thread, shared by 4 waves), ds_write_b128.
// A/B fragment layout for 32x32x16 (family pattern of the R1-verified
// 16x16x32): lane l holds A[m=l&31][k=8*(l>>5)+j], j=0..7. C/D layout
// HW-verified (m74/m101): col=lane&31, row=(reg&3)+8*(reg>>2)+4*(lane>>5).
__global__ __launch_bounds__(256, 2) void gemm_fused(
    const float* __restrict__ X,            // [BATCH][ISZ] fp32
    const unsigned short* __restrict__ Bm,  // [OSZ][KDIM] bf16 bits
    unsigned short* __restrict__ Cp,        // [SPLITK][M][N] bf16 partials
    int M, int N, int K)
{
    __shared__ __align__(16) unsigned short As[2][TM * BK];   // 2 x 16 KB
    __shared__ __align__(16) unsigned short Bs[2][TN * BK];   // 2 x 16 KB

    const int tid  = threadIdx.x;
    const int wave = tid >> 6;
    const int lane = tid & 63;
    const int wm   = (wave >> 1) * 64;      // wave row offset in tile
    const int wn   = (wave & 1) * 64;       // wave col offset in tile

    const int    m0    = blockIdx.x * TM;
    const size_t baseB = (size_t)blockIdx.y * TN * K;
    const int kper  = K / SPLITK;           // 1024
    const int kbeg  = blockIdx.z * kper;
    const int niter = kper / BK;            // 16

    f32x16 acc[2][2] = {};

    const int nrow = lane & 31;             // m/n within 32x32 tile
    const int kc   = lane >> 5;             // 16B-chunk column offset (0/1)

    // A-compute assignment: thread t -> row xr = t>>1, chunk cols xc..xc+3
    const int xr = tid >> 1;
    const int xc = (tid & 1) * 4;

    // B staging: 128x64 bf16 = 16 KB = 1024 chunks of 16B; 256 thr x 4 its.
    auto stageB = [&](int k0, int buf) {
        #pragma unroll
        for (int it = 0; it < 4; ++it) {
            int s    = it * 256 + tid;
            int row  = s >> 3;
            int csrc = (s & 7) ^ (row & 7);
            const unsigned short* gB = Bm + baseB + (size_t)row * K + k0 + csrc * 8;
            unsigned short* lB = &Bs[buf][0] + (size_t)(it * 256 + wave * 64) * 8;
            __builtin_amdgcn_global_load_lds(
                (const __attribute__((address_space(1))) uint32_t*)gB,
                (__attribute__((address_space(3))) uint32_t*)lB, 16, 0, 0);
        }
    };

    // A staging: jacobi8(tanh(x)) for chunk (xr, xc..xc+3) -> As[buf]
    auto stageA = [&](int k0, int buf) {
        const int i0 = k0 >> 3;
        float4 xv = *reinterpret_cast<const float4*>(
            X + (size_t)(m0 + xr) * ISZ + i0 + xc);
        const float xs[4] = {xv.x, xv.y, xv.z, xv.w};
        #pragma unroll
        for (int j = 0; j < 4; ++j) {
            // tanh(x) = 1 - 2/(exp(2x)+1); err ~1e-6 << bf16 ulp
            float e  = __expf(2.0f * xs[j]);
            float t  = 1.0f - 2.0f * __builtin_amdgcn_rcpf(e + 1.0f);
            float p1 = 2.0f * t;
            float p2 = (1.875f     * t) * p1 - 0.75f;
            float p3 = (1.8666667f * t) * p2 - 0.8f        * p1;
            float p4 = (1.875f     * t) * p3 - 0.83333333f * p2;
            float p5 = (1.8857143f * t) * p4 - 0.85714287f * p3;
            float p6 = (1.8958333f * t) * p5 - 0.875f      * p4;
            float p7 = (1.9047619f * t) * p6 - 0.88888889f * p5;
            uint4 o;
            o.x = 0x3F80u | ((uint32_t)f2bf(p1) << 16);
            o.y = (uint32_t)f2bf(p2) | ((uint32_t)f2bf(p3) << 16);
            o.z = (uint32_t)f2bf(p4) | ((uint32_t)f2bf(p5) << 16);
            o.w = (uint32_t)f2bf(p6) | ((uint32_t)f2bf(p7) << 16);
            int slot = xr * 8 + ((xc + j) ^ (xr & 7));
            *reinterpret_cast<uint4*>(&As[buf][0] + (size_t)slot * 8) = o;
        }
    };

    stageB(kbeg, 0);
    stageA(kbeg, 0);
    __syncthreads();

    for (int kt = 0; kt < niter; ++kt) {
        const int k0 = kbeg + kt * BK;
        const int p  = kt & 1;
        if (kt + 1 < niter) {
            stageB(k0 + BK, 1 - p);     // async DMA flies through MFMA phase
            stageA(k0 + BK, 1 - p);     // VALU overlaps MFMA (m114)
        }

        const unsigned short* Ap = &As[p][0];
        const unsigned short* Bp = &Bs[p][0];
        #pragma unroll
        for (int ks = 0; ks < BK; ks += 16) {       // 4 steps of K=16
            bf16x8 aF[2], bF[2];
            const int cbase = (ks >> 3) + kc;       // chunk col in [0,8)
            #pragma unroll
            for (int mi = 0; mi < 2; ++mi) {
                int r = wm + mi * 32 + nrow;
                int slot = r * 8 + (cbase ^ (r & 7));
                aF[mi] = *reinterpret_cast<const bf16x8*>(Ap + (size_t)slot * 8);
            }
            #pragma unroll
            for (int ni = 0; ni < 2; ++ni) {
                int r = wn + ni * 32 + nrow;
                int slot = r * 8 + (cbase ^ (r & 7));
                bF[ni] = *reinterpret_cast<const bf16x8*>(Bp + (size_t)slot * 8);
            }
            #pragma unroll
            for (int mi = 0; mi < 2; ++mi)
                #pragma unroll
                for (int ni = 0; ni < 2; ++ni)
                    acc[mi][ni] = __builtin_amdgcn_mfma_f32_32x32x16_bf16(
                        aF[mi], bF[ni], acc[mi][ni], 0, 0, 0);
        }
        __syncthreads();   // completes buf[1-p] stage; fences buf[p] reuse
    }

    // bf16 partials, plain stores (R3: atomics = ~50us TCC serialization).
    // 32x32 C/D layout (m74/m101-verified):
    //   col = lane&31, row = (reg&3) + 8*(reg>>2) + 4*(lane>>5)
    unsigned short* Cz = Cp + (size_t)blockIdx.z * M * N;
    const int orow = blockIdx.x * TM + wm + 4 * (lane >> 5);
    const int ocol = blockIdx.y * TN + wn + (lane & 31);
    #pragma unroll
    for (int mi = 0; mi < 2; ++mi)
        #pragma unroll
        for (int ni = 0; ni < 2; ++ni)
            #pragma unroll
            for (int reg = 0; reg < 16; ++reg) {
                int row = orow + mi * 32 + (reg & 3) + 8 * (reg >> 2);
                int col = ocol + ni * 32;
                Cz[(size_t)row * N + col] = f2bf(acc[mi][ni][reg]);
            }
}

// out = sum over SPLITK bf16 partials (fp32 accumulate), 4 outputs/thread
__global__ __launch_bounds__(256) void reduce_k(
    const unsigned short* __restrict__ part, float* __restrict__ out, int n4)
{
    int idx = blockIdx.x * 256 + threadIdx.x;
    if (idx >= n4) return;
    const uint2* p = reinterpret_cast<const uint2*>(part);   // 4 bf16 / uint2
    float s0 = 0.f, s1 = 0.f, s2 = 0.f, s3 = 0.f;
    #pragma unroll
    for (int z = 0; z < SPLITK; ++z) {
        uint2 v = p[(size_t)z * n4 + idx];
        s0 += __uint_as_float((v.x & 0xFFFFu) << 16);
        s1 += __uint_as_float(v.x & 0xFFFF0000u);
        s2 += __uint_as_float((v.y & 0xFFFFu) << 16);
        s3 += __uint_as_float(v.y & 0xFFFF0000u);
    }
    float4 o = {s0, s1, s2, s3};
    reinterpret_cast<float4*>(out)[idx] = o;
}

extern "C" void kernel_launch(void* const* d_in, const int* in_sizes, int n_in,
                              void* d_out, int out_size, void* d_ws, size_t ws_size,
                              hipStream_t stream)
{
    const float* x    = (const float*)d_in[0];   // [4096][512]
    const float* coef = (const float*)d_in[1];   // [512][512][8]
    float* out = (float*)d_out;                  // [4096][512]

    // workspace: bf16 partials [SPLITK][4096][512] (16 MB) + coef bf16 (4 MB)
    unsigned short* part  = (unsigned short*)d_ws;
    unsigned short* coefb = part + (size_t)SPLITK * BATCH * OSZ;

    int n4c = (OSZ * KDIM) / 4;                  // 524,288
    convert_bf16<<<(n4c + 255) / 256, 256, 0, stream>>>(coef, coefb, n4c);

    dim3 grid(BATCH / TM, OSZ / TN, SPLITK);     // 32 x 4 x 4 = 512 blocks
    gemm_fused<<<grid, 256, 0, stream>>>(x, coefb, part, BATCH, OSZ, KDIM);

    int n4r = (BATCH * OSZ) / 4;                 // 524,288
    reduce_k<<<(n4r + 255) / 256, 256, 0, stream>>>(part, out, n4r);
}